// Round 1
// baseline (9276.306 us; speedup 1.0000x reference)
//
#include <hip/hip_runtime.h>

#define B_ 64
#define T_ 512
#define I_ 256
#define H_ 1024
#define O_ 256

typedef _Float16 f16;
typedef _Float16 f16x2 __attribute__((ext_vector_type(2)));
typedef _Float16 f16x8 __attribute__((ext_vector_type(8)));

#if __has_builtin(__builtin_amdgcn_fdot2)
__device__ __forceinline__ float dot2f(f16x2 a, f16x2 b, float c) {
  return __builtin_amdgcn_fdot2(a, b, c, false);
}
#else
__device__ __forceinline__ float dot2f(f16x2 a, f16x2 b, float c) {
  return fmaf((float)a[0], (float)b[0], fmaf((float)a[1], (float)b[1], c));
}
#endif

__device__ __forceinline__ float dot8f(f16x8 w, f16x8 v, float acc) {
  acc = dot2f(__builtin_shufflevector(w, w, 0, 1), __builtin_shufflevector(v, v, 0, 1), acc);
  acc = dot2f(__builtin_shufflevector(w, w, 2, 3), __builtin_shufflevector(v, v, 2, 3), acc);
  acc = dot2f(__builtin_shufflevector(w, w, 4, 5), __builtin_shufflevector(v, v, 4, 5), acc);
  acc = dot2f(__builtin_shufflevector(w, w, 6, 7), __builtin_shufflevector(v, v, 6, 7), acc);
  return acc;
}

// src [R][K] fp32 row-major -> dst [K/8][R] of f16x8 (transposed 8-chunk layout)
// so that in the main kernel, lane j reads dst[c*R + j]: 64 lanes x 16B contiguous.
__global__ void convert_T8(const float* __restrict__ src, f16* __restrict__ dst,
                           int R, int K) {
  int K8 = K >> 3;
  int total = R * K8;
  int idx = blockIdx.x * blockDim.x + threadIdx.x;
  if (idx >= total) return;
  int r = idx / K8;
  int k8 = idx - r * K8;  // consecutive lanes -> consecutive k8 -> coalesced src reads
  const float4* s = reinterpret_cast<const float4*>(src + (size_t)r * K + (size_t)k8 * 8);
  float4 a = s[0], b = s[1];
  f16x8 v;
  v[0] = (f16)a.x; v[1] = (f16)a.y; v[2] = (f16)a.z; v[3] = (f16)a.w;
  v[4] = (f16)b.x; v[5] = (f16)b.y; v[6] = (f16)b.z; v[7] = (f16)b.w;
  reinterpret_cast<f16x8*>(dst)[(size_t)k8 * R + r] = v;
}

// One workgroup per batch element. Thread j owns hidden row j.
// h lives in LDS (f16); per step: acc = bias + Wih[j,:]@x_t + Whh[j,:]@h; h[j]=tanh(acc).
__global__ __launch_bounds__(1024) void rnn_f16(
    const float* __restrict__ x,     // [B][T][I] fp32
    const f16* __restrict__ wihT,    // [I/8][H] of f16x8
    const f16* __restrict__ whhT,    // [H/8][H] of f16x8
    const float* __restrict__ bih,
    const float* __restrict__ bhh,
    const f16* __restrict__ wfcT,    // [H/8][O] of f16x8
    const float* __restrict__ bfc,
    float* __restrict__ out) {       // [B][O] fp32
  __shared__ f16 hs[H_];
  __shared__ f16 xs[I_];
  const int b = blockIdx.x;
  const int j = threadIdx.x;

  const float bias = bih[j] + bhh[j];
  hs[j] = (f16)0.f;

  const f16x8* wih_p = reinterpret_cast<const f16x8*>(wihT) + j;
  const f16x8* whh_p = reinterpret_cast<const f16x8*>(whhT) + j;
  const f16x8* xv = reinterpret_cast<const f16x8*>(xs);
  const f16x8* hv = reinterpret_cast<const f16x8*>(hs);
  const float* xrow = x + (size_t)b * T_ * I_;

  for (int t = 0; t < T_; ++t) {
    if (j < I_) xs[j] = (f16)xrow[t * I_ + j];
    __syncthreads();  // xs staged; hs writes from prev step visible

    float acc = bias;
#pragma unroll 8
    for (int c = 0; c < I_ / 8; ++c) {
      acc = dot8f(wih_p[c * H_], xv[c], acc);
    }
#pragma unroll 8
    for (int c = 0; c < H_ / 8; ++c) {
      acc = dot8f(whh_p[c * H_], hv[c], acc);
    }
    float hn = tanhf(acc);
    __syncthreads();  // all reads of hs complete before overwrite
    hs[j] = (f16)hn;
  }
  __syncthreads();

  // head: out[b][o] = h_last @ W_fc[o,:] + b_fc[o]
  if (j < O_) {
    const f16x8* wfc_p = reinterpret_cast<const f16x8*>(wfcT) + j;
    float acc = bfc[j];
#pragma unroll 8
    for (int c = 0; c < H_ / 8; ++c) {
      acc = dot8f(wfc_p[c * O_], hv[c], acc);
    }
    out[(size_t)b * O_ + j] = acc;
  }
}

// Pure-fp32 fallback (used only if workspace is too small for converted weights).
__global__ __launch_bounds__(1024) void rnn_fp32(
    const float* __restrict__ x,
    const float* __restrict__ Wih, const float* __restrict__ Whh,
    const float* __restrict__ bih, const float* __restrict__ bhh,
    const float* __restrict__ Wfc, const float* __restrict__ bfc,
    float* __restrict__ out) {
  __shared__ float hs[H_];
  __shared__ float xs[I_];
  const int b = blockIdx.x;
  const int j = threadIdx.x;
  const float bias = bih[j] + bhh[j];
  hs[j] = 0.f;
  const float4* wih_r = reinterpret_cast<const float4*>(Wih + (size_t)j * I_);
  const float4* whh_r = reinterpret_cast<const float4*>(Whh + (size_t)j * H_);
  const float4* xv = reinterpret_cast<const float4*>(xs);
  const float4* hv = reinterpret_cast<const float4*>(hs);
  const float* xrow = x + (size_t)b * T_ * I_;
  for (int t = 0; t < T_; ++t) {
    if (j < I_) xs[j] = xrow[t * I_ + j];
    __syncthreads();
    float acc = bias;
#pragma unroll 4
    for (int c = 0; c < I_ / 4; ++c) {
      float4 w = wih_r[c], v = xv[c];
      acc = fmaf(w.x, v.x, acc); acc = fmaf(w.y, v.y, acc);
      acc = fmaf(w.z, v.z, acc); acc = fmaf(w.w, v.w, acc);
    }
#pragma unroll 4
    for (int c = 0; c < H_ / 4; ++c) {
      float4 w = whh_r[c], v = hv[c];
      acc = fmaf(w.x, v.x, acc); acc = fmaf(w.y, v.y, acc);
      acc = fmaf(w.z, v.z, acc); acc = fmaf(w.w, v.w, acc);
    }
    float hn = tanhf(acc);
    __syncthreads();
    hs[j] = hn;
  }
  __syncthreads();
  if (j < O_) {
    float acc = bfc[j];
    const float4* wfc_r = reinterpret_cast<const float4*>(Wfc + (size_t)j * H_);
    for (int c = 0; c < H_ / 4; ++c) {
      float4 w = wfc_r[c], v = hv[c];
      acc = fmaf(w.x, v.x, acc); acc = fmaf(w.y, v.y, acc);
      acc = fmaf(w.z, v.z, acc); acc = fmaf(w.w, v.w, acc);
    }
    out[(size_t)b * O_ + j] = acc;
  }
}

extern "C" void kernel_launch(void* const* d_in, const int* in_sizes, int n_in,
                              void* d_out, int out_size, void* d_ws, size_t ws_size,
                              hipStream_t stream) {
  const float* x   = (const float*)d_in[0];
  const float* Wih = (const float*)d_in[1];
  const float* Whh = (const float*)d_in[2];
  const float* bih = (const float*)d_in[3];
  const float* bhh = (const float*)d_in[4];
  const float* Wfc = (const float*)d_in[5];
  const float* bfc = (const float*)d_in[6];
  float* out = (float*)d_out;

  const size_t n_wih = (size_t)H_ * I_;  // 262144
  const size_t n_whh = (size_t)H_ * H_;  // 1048576
  const size_t n_wfc = (size_t)O_ * H_;  // 262144
  const size_t need = (n_wih + n_whh + n_wfc) * sizeof(f16);  // 3 MB

  if (ws_size >= need) {
    f16* wihT = (f16*)d_ws;
    f16* whhT = wihT + n_wih;
    f16* wfcT = whhT + n_whh;
    const int thr = 256;
    convert_T8<<<(int)((n_wih / 8 + thr - 1) / thr), thr, 0, stream>>>(Wih, wihT, H_, I_);
    convert_T8<<<(int)((n_whh / 8 + thr - 1) / thr), thr, 0, stream>>>(Whh, whhT, H_, H_);
    convert_T8<<<(int)((n_wfc / 8 + thr - 1) / thr), thr, 0, stream>>>(Wfc, wfcT, O_, H_);
    rnn_f16<<<B_, 1024, 0, stream>>>(x, wihT, whhT, bih, bhh, wfcT, bfc, out);
  } else {
    rnn_fp32<<<B_, 1024, 0, stream>>>(x, Wih, Whh, bih, bhh, Wfc, bfc, out);
  }
}